// Round 4
// baseline (340.662 us; speedup 1.0000x reference)
//
#include <hip/hip_runtime.h>
#include <hip/hip_bf16.h>

#define N_NODES  100000
#define N_EDGES  640000
#define N_GRAPHS 2048
#define HID      128
#define NB_SCAN  391   // ceil(N_NODES/256)
#define TILE     32    // nodes per fused agg+mm tile (100000 = 3125 * 32, no tail)
#define LDW      136   // padded LDS row (halves): 272 B, 16B-aligned

typedef _Float16 half_t;
typedef __attribute__((ext_vector_type(4))) _Float16 half4;
typedef __attribute__((ext_vector_type(8))) _Float16 half8;
typedef __attribute__((ext_vector_type(4))) float floatx4;

// ---------------------------------------------------------------- fused prep: degree + x pack + weight convert
__global__ void k_prep(const int* __restrict__ col, int* __restrict__ deg,
                       const float* __restrict__ x, float4* __restrict__ xp,
                       const float* __restrict__ W2, const float* __restrict__ W3,
                       const float* __restrict__ W4, half_t* __restrict__ Wt) {
    int idx = blockIdx.x * 256 + threadIdx.x;
    if (idx < N_EDGES) atomicAdd(&deg[col[idx]], 1);
    if (idx < N_NODES) xp[idx] = make_float4(x[idx * 3 + 0], x[idx * 3 + 1], x[idx * 3 + 2], 0.f);
    if (idx < 3 * 128 * 128) {
        int l = idx >> 14;
        int e = idx & 16383;
        int cin = e >> 7, cout = e & 127;
        const float* W = (l == 0) ? W2 : ((l == 1) ? W3 : W4);
        Wt[l * 16384 + cout * 128 + cin] = (half_t)W[cin * 128 + cout];
    }
}

// ---------------------------------------------------------------- scan (exclusive prefix sum of deg -> row_ptr) + dinv
__global__ void k_scan1(const int* __restrict__ deg, int* __restrict__ row_ptr,
                        int* __restrict__ bsum, float* __restrict__ dinv) {
    __shared__ int s[256];
    int tid = threadIdx.x;
    int i = blockIdx.x * 256 + tid;
    int d = (i < N_NODES) ? deg[i] : 0;
    if (i < N_NODES) dinv[i] = rsqrtf((float)(d + 1));  // +1 self loop
    s[tid] = d;
    __syncthreads();
    for (int off = 1; off < 256; off <<= 1) {
        int v = (tid >= off) ? s[tid - off] : 0;
        __syncthreads();
        s[tid] += v;
        __syncthreads();
    }
    if (i < N_NODES) row_ptr[i] = s[tid] - d;   // exclusive within block
    if (tid == 255) bsum[blockIdx.x] = s[255];
}

__global__ void k_scan2(int* __restrict__ bsum) {
    __shared__ int s[512];
    int tid = threadIdx.x;
    int v = (tid < NB_SCAN) ? bsum[tid] : 0;
    s[tid] = v;
    __syncthreads();
    for (int off = 1; off < 512; off <<= 1) {
        int u = (tid >= off) ? s[tid - off] : 0;
        __syncthreads();
        s[tid] += u;
        __syncthreads();
    }
    if (tid < NB_SCAN) bsum[tid] = s[tid] - v;  // exclusive block offsets
}

__global__ void k_scan3(int* __restrict__ row_ptr, const int* __restrict__ bsum) {
    int i = blockIdx.x * 256 + threadIdx.x;
    if (i < N_NODES) row_ptr[i] += bsum[blockIdx.x];
    if (i == N_NODES) row_ptr[N_NODES] = N_EDGES;
}

// ---------------------------------------------------------------- CSR scatter: packed (src, weight) int2 -> ONE 8B store
__global__ void k_scatter(const int* __restrict__ row, const int* __restrict__ col,
                          const int* __restrict__ row_ptr, int* __restrict__ cursor,
                          const float* __restrict__ dinv, int2* __restrict__ epair) {
    int e = blockIdx.x * blockDim.x + threadIdx.x;
    if (e >= N_EDGES) return;
    int c = col[e];
    int r = row[e];
    int p = row_ptr[c] + atomicAdd(&cursor[c], 1);
    epair[p] = make_int2(r, __float_as_int(dinv[r] * dinv[c]));
}

// ---------------------------------------------------------------- fused: aggregate x + layer-1 dense -> fp16 h1
__global__ __launch_bounds__(256) void k_aggx_fc1(const float4* __restrict__ xp,
                                                  const int* __restrict__ row_ptr,
                                                  const int2* __restrict__ epair,
                                                  const float* __restrict__ dinv,
                                                  const float* __restrict__ W1,
                                                  const float* __restrict__ b1,
                                                  half_t* __restrict__ h) {
    __shared__ float sax[256][3];
    int t = threadIdx.x;
    int nb = blockIdx.x * 256;
    int i = nb + t;
    if (i < N_NODES) {
        float di = dinv[i];
        float sw = di * di;
        float4 xv = xp[i];
        float a0 = sw * xv.x, a1 = sw * xv.y, a2 = sw * xv.z;
        int s = row_ptr[i], e = row_ptr[i + 1];
        int k = s;
        for (; k + 4 <= e; k += 4) {
            int2 pr[4];
#pragma unroll
            for (int r = 0; r < 4; r++) pr[r] = epair[k + r];
            float4 bx[4];
#pragma unroll
            for (int r = 0; r < 4; r++) bx[r] = xp[pr[r].x];
#pragma unroll
            for (int r = 0; r < 4; r++) {
                float w = __int_as_float(pr[r].y);
                a0 += w * bx[r].x;
                a1 += w * bx[r].y;
                a2 += w * bx[r].z;
            }
        }
        for (; k < e; k++) {
            int2 pr = epair[k];
            float w = __int_as_float(pr.y);
            float4 bx = xp[pr.x];
            a0 += w * bx.x;
            a1 += w * bx.y;
            a2 += w * bx.z;
        }
        sax[t][0] = a0; sax[t][1] = a1; sax[t][2] = a2;
    }
    __syncthreads();
    int cq = t & 31, g8 = t >> 5;
    const float4* W14 = (const float4*)W1;
    float4 w0 = W14[cq], w1 = W14[32 + cq], w2 = W14[64 + cq];
    float4 bb = ((const float4*)b1)[cq];
    for (int pass = 0; pass < 32; pass++) {
        int local = pass * 8 + g8;
        int node = nb + local;
        if (node >= N_NODES) break;
        float x0 = sax[local][0], x1 = sax[local][1], x2 = sax[local][2];
        half4 o;
        o.x = (half_t)fmaxf(bb.x + x0 * w0.x + x1 * w1.x + x2 * w2.x, 0.f);
        o.y = (half_t)fmaxf(bb.y + x0 * w0.y + x1 * w1.y + x2 * w2.y, 0.f);
        o.z = (half_t)fmaxf(bb.z + x0 * w0.z + x1 * w1.z + x2 * w2.z, 0.f);
        o.w = (half_t)fmaxf(bb.w + x0 * w0.w + x1 * w1.w + x2 * w2.w, 0.f);
        ((half4*)h)[(size_t)node * 32 + cq] = o;
    }
}

// ---------------------------------------------------------------- FUSED layer: h_out = relu(Agg(h_in) @ W + b)
// TILE=32: 16 groups x 16 lanes gather 2 nodes each into LDS (depth-4 row
// prefetch = 4 rows in flight per group); 32x128x128 MFMA (wave owns a 16x64
// quadrant); relu-stage + coalesced write. launch_bounds(256,6): 24 waves/CU
// with enough VGPR for the quad pipeline (no spill).
__global__ __launch_bounds__(256, 6) void k_agg_mm(const half_t* __restrict__ h_in,
                                                   const int* __restrict__ row_ptr,
                                                   const int2* __restrict__ epair,
                                                   const float* __restrict__ dinv,
                                                   const half_t* __restrict__ Wt,
                                                   const float* __restrict__ b,
                                                   half_t* __restrict__ h_out) {
    __shared__ __align__(16) half_t gs[TILE][LDW];   // 8.7 KB
    int tid = threadIdx.x;
    int n0 = blockIdx.x * TILE;
    int lane16 = tid & 15;
    int gidx = tid >> 4;                  // 16 gather groups
    const half8* h8 = (const half8*)h_in;

    // ---- Phase A: gather (2 nodes per group, depth-4 row prefetch)
#pragma unroll
    for (int p = 0; p < 2; p++) {
        int local = p * 16 + gidx;
        int i = n0 + local;              // always < N_NODES (32 | 100000)
        float di = dinv[i];
        float sw = di * di;
        half8 v = h8[(size_t)i * 16 + lane16];
        float acc[8];
#pragma unroll
        for (int c = 0; c < 8; c++) acc[c] = sw * (float)v[c];
        int s = row_ptr[i], e = row_ptr[i + 1];
        if (s < e) {
            int em1 = e - 1;
            int2 p0 = epair[s];
            int2 p1 = epair[min(s + 1, em1)];
            int2 p2 = epair[min(s + 2, em1)];
            int2 p3 = epair[min(s + 3, em1)];
            float w0 = __int_as_float(p0.y);
            float w1 = (s + 1 < e) ? __int_as_float(p1.y) : 0.f;
            float w2 = (s + 2 < e) ? __int_as_float(p2.y) : 0.f;
            float w3 = (s + 3 < e) ? __int_as_float(p3.y) : 0.f;
            half8 u0 = h8[(size_t)p0.x * 16 + lane16];
            half8 u1 = h8[(size_t)p1.x * 16 + lane16];
            half8 u2 = h8[(size_t)p2.x * 16 + lane16];
            half8 u3 = h8[(size_t)p3.x * 16 + lane16];
            for (int k = s; k < e; k += 4) {
                int kn = k + 4;
                int2 q0 = epair[min(kn, em1)];
                int2 q1 = epair[min(kn + 1, em1)];
                float x0 = (kn     < e) ? __int_as_float(q0.y) : 0.f;
                float x1 = (kn + 1 < e) ? __int_as_float(q1.y) : 0.f;
                half8 m0 = h8[(size_t)q0.x * 16 + lane16];
                half8 m1 = h8[(size_t)q1.x * 16 + lane16];
#pragma unroll
                for (int c = 0; c < 8; c++) acc[c] += w0 * (float)u0[c] + w1 * (float)u1[c];
                int2 q2 = epair[min(kn + 2, em1)];
                int2 q3 = epair[min(kn + 3, em1)];
                float x2 = (kn + 2 < e) ? __int_as_float(q2.y) : 0.f;
                float x3 = (kn + 3 < e) ? __int_as_float(q3.y) : 0.f;
                half8 m2 = h8[(size_t)q2.x * 16 + lane16];
                half8 m3 = h8[(size_t)q3.x * 16 + lane16];
#pragma unroll
                for (int c = 0; c < 8; c++) acc[c] += w2 * (float)u2[c] + w3 * (float)u3[c];
                u0 = m0; u1 = m1; u2 = m2; u3 = m3;
                w0 = x0; w1 = x1; w2 = x2; w3 = x3;
            }
        }
        half8 av;
#pragma unroll
        for (int c = 0; c < 8; c++) av[c] = (half_t)acc[c];
        *(half8*)(&gs[local][lane16 * 8]) = av;
    }
    __syncthreads();

    // ---- Phase B: MFMA 32x128x128 from LDS; wave wv owns rows (wv&1)*16..+16,
    //      cols (wv>>1)*64..+64
    int wv = tid >> 6;          // wave 0..3
    int ln = tid & 15;          // A-m / B-n / D-col
    int q  = (tid >> 4) & 3;    // quad
    int rbase = (wv & 1) * 16;
    int cbase = (wv >> 1) * 64;
    floatx4 C[4];
#pragma unroll
    for (int t = 0; t < 4; t++) {
        float bn = b[cbase + t * 16 + ln];
        C[t].x = bn; C[t].y = bn; C[t].z = bn; C[t].w = bn;
    }
#pragma unroll
    for (int kq = 0; kq < 4; kq++) {
        half8 a = *(const half8*)(&gs[rbase + ln][kq * 32 + q * 8]);
#pragma unroll
        for (int t = 0; t < 4; t++) {
            half8 bf = *(const half8*)(Wt + (size_t)(cbase + t * 16 + ln) * 128 + kq * 32 + q * 8);
            C[t] = __builtin_amdgcn_mfma_f32_16x16x32_f16(a, bf, C[t], 0, 0, 0);
        }
    }

    // ---- Phase C: stage relu(D) back into gs, then coalesced write
    __syncthreads();
#pragma unroll
    for (int t = 0; t < 4; t++) {
#pragma unroll
        for (int reg = 0; reg < 4; reg++) {
            float dv = (reg == 0) ? C[t].x : (reg == 1) ? C[t].y : (reg == 2) ? C[t].z : C[t].w;
            gs[rbase + q * 4 + reg][cbase + t * 16 + ln] = (half_t)fmaxf(dv, 0.f);
        }
    }
    __syncthreads();
#pragma unroll
    for (int v2 = 0; v2 < 2; v2++) {
        int idx = v2 * 256 + tid;
        int r0 = idx >> 4;            // 0..31
        int c0 = idx & 15;            // int4 within row
        int4* dst = (int4*)(h_out + (size_t)(n0 + r0) * 128);
        const int4* srcp = (const int4*)(&gs[r0][0]);
        dst[c0] = srcp[c0];
    }
}

// ---------------------------------------------------------------- fused mean-pool + final FC (no atomics, vectorized)
__global__ __launch_bounds__(128) void k_pool_final(const half_t* __restrict__ h,
                                                    const int* __restrict__ batch,
                                                    const float* __restrict__ Wfc,
                                                    const float* __restrict__ bfc,
                                                    float* __restrict__ out) {
    __shared__ float sred[8][128];
    __shared__ float red[128][4];
    __shared__ int sb_s, eb_s;
    int g = blockIdx.x, t = threadIdx.x;
    if (t == 0) {
        int lo = 0, hi = N_NODES;
        while (lo < hi) { int mid = (lo + hi) >> 1; if (batch[mid] < g) lo = mid + 1; else hi = mid; }
        sb_s = lo;
        hi = N_NODES;
        while (lo < hi) { int mid = (lo + hi) >> 1; if (batch[mid] < g + 1) lo = mid + 1; else hi = mid; }
        eb_s = lo;
    }
    __syncthreads();
    int sb = sb_s, eb = eb_s;
    int lane16 = t & 15, slot = t >> 4;
    const half8* h8 = (const half8*)h;
    float acc[8];
#pragma unroll
    for (int c = 0; c < 8; c++) acc[c] = 0.f;
    for (int n = sb + slot; n < eb; n += 8) {
        half8 v = h8[(size_t)n * 16 + lane16];
#pragma unroll
        for (int c = 0; c < 8; c++) acc[c] += (float)v[c];
    }
#pragma unroll
    for (int c = 0; c < 8; c++) sred[slot][lane16 * 8 + c] = acc[c];
    __syncthreads();
    float pv = 0.f;
#pragma unroll
    for (int s2 = 0; s2 < 8; s2++) pv += sred[s2][t];
    float inv = 1.0f / fmaxf((float)(eb - sb), 1.0f);
    float v = pv * inv;
    float4 w = ((const float4*)Wfc)[t];
    red[t][0] = v * w.x; red[t][1] = v * w.y; red[t][2] = v * w.z; red[t][3] = v * w.w;
    __syncthreads();
    for (int s = 64; s > 0; s >>= 1) {
        if (t < s) {
            red[t][0] += red[t + s][0];
            red[t][1] += red[t + s][1];
            red[t][2] += red[t + s][2];
            red[t][3] += red[t + s][3];
        }
        __syncthreads();
    }
    if (t < 4) out[g * 4 + t] = red[0][t] + bfc[t];
}

// ================================================================ launch
extern "C" void kernel_launch(void* const* d_in, const int* in_sizes, int n_in,
                              void* d_out, int out_size, void* d_ws, size_t ws_size,
                              hipStream_t stream) {
    const float* x     = (const float*)d_in[0];
    const int*   ei    = (const int*)d_in[1];
    const int*   row   = ei;             // source
    const int*   col   = ei + N_EDGES;   // target (aggregation side)
    const int*   batch = (const int*)d_in[2];
    const float* W1 = (const float*)d_in[3];
    const float* b1 = (const float*)d_in[4];
    const float* W2 = (const float*)d_in[5];
    const float* b2 = (const float*)d_in[6];
    const float* W3 = (const float*)d_in[7];
    const float* b3 = (const float*)d_in[8];
    const float* W4 = (const float*)d_in[9];
    const float* b4 = (const float*)d_in[10];
    const float* Wfc = (const float*)d_in[11];
    const float* bfc = (const float*)d_in[12];
    float* out = (float*)d_out;

    char* ws = (char*)d_ws;
    size_t off = 0;
    auto take = [&](size_t bytes) -> char* {
        char* p = ws + off;
        off = (off + bytes + 255) & ~(size_t)255;
        return p;
    };
    // deg, cursor contiguous -> one memset
    int*    deg     = (int*)take(N_NODES * 4);
    int*    cursor  = (int*)take(N_NODES * 4);
    size_t  zspan   = (size_t)((char*)cursor + N_NODES * 4 - (char*)deg);
    int*    row_ptr = (int*)take((N_NODES + 1) * 4);
    int*    bsum    = (int*)take(512 * 4);
    float*  dinv    = (float*)take(N_NODES * 4);
    float4* xp      = (float4*)take((size_t)N_NODES * 16);
    int2*   epair   = (int2*)take((size_t)N_EDGES * 8);
    half_t* wt16    = (half_t*)take((size_t)3 * 128 * 128 * 2);
    half_t* bufA    = (half_t*)take((size_t)N_NODES * 128 * 2);
    half_t* bufB    = (half_t*)take((size_t)N_NODES * 128 * 2);

    hipMemsetAsync(deg, 0, zspan, stream);

    k_prep<<<(N_EDGES + 255) / 256, 256, 0, stream>>>(col, deg, x, xp, W2, W3, W4, wt16);
    k_scan1<<<NB_SCAN, 256, 0, stream>>>(deg, row_ptr, bsum, dinv);
    k_scan2<<<1, 512, 0, stream>>>(bsum);
    k_scan3<<<NB_SCAN, 256, 0, stream>>>(row_ptr, bsum);
    k_scatter<<<(N_EDGES + 255) / 256, 256, 0, stream>>>(row, col, row_ptr, cursor,
                                                         dinv, epair);
    k_aggx_fc1<<<NB_SCAN, 256, 0, stream>>>(xp, row_ptr, epair, dinv, W1, b1, bufA);

    const int NBF = N_NODES / TILE;   // 3125, exact
    // layer 2: bufA -> bufB ; layer 3: bufB -> bufA ; layer 4: bufA -> bufB
    k_agg_mm<<<NBF, 256, 0, stream>>>(bufA, row_ptr, epair, dinv, wt16,         b2, bufB);
    k_agg_mm<<<NBF, 256, 0, stream>>>(bufB, row_ptr, epair, dinv, wt16 + 16384, b3, bufA);
    k_agg_mm<<<NBF, 256, 0, stream>>>(bufA, row_ptr, epair, dinv, wt16 + 32768, b4, bufB);

    // fused mean-pool + FC (no atomics)
    k_pool_final<<<N_GRAPHS, 128, 0, stream>>>(bufB, batch, Wfc, bfc, out);
}

// Round 5
// 312.791 us; speedup vs baseline: 1.0891x; 1.0891x over previous
//
#include <hip/hip_runtime.h>
#include <hip/hip_bf16.h>

#define N_NODES  100000
#define N_EDGES  640000
#define N_GRAPHS 2048
#define HID      128
#define NB_SCAN  391   // ceil(N_NODES/256)
#define TILE     16    // nodes per fused agg+mm tile (100000 = 6250 * 16, no tail)
#define LDW      136   // padded LDS row (halves): 272 B, 16B-aligned

typedef _Float16 half_t;
typedef __attribute__((ext_vector_type(4))) _Float16 half4;
typedef __attribute__((ext_vector_type(8))) _Float16 half8;
typedef __attribute__((ext_vector_type(4))) float floatx4;

// ---------------------------------------------------------------- fused prep: degree + x pack (fp32 + fp16) + weight convert
__global__ void k_prep(const int* __restrict__ col, int* __restrict__ deg,
                       const float* __restrict__ x, float4* __restrict__ xp,
                       half4* __restrict__ xh,
                       const float* __restrict__ W2, const float* __restrict__ W3,
                       const float* __restrict__ W4, half_t* __restrict__ Wt) {
    int idx = blockIdx.x * 256 + threadIdx.x;
    if (idx < N_EDGES) atomicAdd(&deg[col[idx]], 1);
    if (idx < N_NODES) {
        float x0 = x[idx * 3 + 0], x1 = x[idx * 3 + 1], x2 = x[idx * 3 + 2];
        xp[idx] = make_float4(x0, x1, x2, 0.f);
        half4 hv;
        hv.x = (half_t)x0; hv.y = (half_t)x1; hv.z = (half_t)x2; hv.w = (half_t)0.f;
        xh[idx] = hv;      // 8-B rows: 800 KB total -> L2-resident gather
    }
    if (idx < 3 * 128 * 128) {
        int l = idx >> 14;
        int e = idx & 16383;
        int cin = e >> 7, cout = e & 127;
        const float* W = (l == 0) ? W2 : ((l == 1) ? W3 : W4);
        Wt[l * 16384 + cout * 128 + cin] = (half_t)W[cin * 128 + cout];
    }
}

// ---------------------------------------------------------------- scan1: per-block inclusive scan of deg + dinv
__global__ void k_scan1(const int* __restrict__ deg, int* __restrict__ row_ptr,
                        int* __restrict__ bsum, float* __restrict__ dinv) {
    __shared__ int s[256];
    int tid = threadIdx.x;
    int i = blockIdx.x * 256 + tid;
    int d = (i < N_NODES) ? deg[i] : 0;
    if (i < N_NODES) dinv[i] = rsqrtf((float)(d + 1));  // +1 self loop
    s[tid] = d;
    __syncthreads();
    for (int off = 1; off < 256; off <<= 1) {
        int v = (tid >= off) ? s[tid - off] : 0;
        __syncthreads();
        s[tid] += v;
        __syncthreads();
    }
    if (i < N_NODES) row_ptr[i] = s[tid] - d;   // exclusive within block
    if (tid == 255) bsum[blockIdx.x] = s[255];  // block total
}

// ---------------------------------------------------------------- scan3: per-block reduce of preceding block totals + fixup
// (replaces old scan2+scan3 pair: each block sums bsum[0..bid-1] itself)
__global__ void k_scan3(int* __restrict__ row_ptr, const int* __restrict__ bsum) {
    __shared__ int sred[256];
    int t = threadIdx.x, bid = blockIdx.x;
    int partial = 0;
    if (t < bid) partial += bsum[t];
    if (t + 256 < bid) partial += bsum[t + 256];   // bid <= 390, index <= 389
    sred[t] = partial;
    __syncthreads();
    for (int s = 128; s > 0; s >>= 1) {
        if (t < s) sred[t] += sred[t + s];
        __syncthreads();
    }
    int add = sred[0];
    int i = bid * 256 + t;
    if (i < N_NODES) row_ptr[i] += add;
    if (i == N_NODES) row_ptr[N_NODES] = N_EDGES;
}

// ---------------------------------------------------------------- CSR scatter: packed (src, weight) int2 -> ONE 8B store
__global__ void k_scatter(const int* __restrict__ row, const int* __restrict__ col,
                          const int* __restrict__ row_ptr, int* __restrict__ cursor,
                          const float* __restrict__ dinv, int2* __restrict__ epair) {
    int e = blockIdx.x * blockDim.x + threadIdx.x;
    if (e >= N_EDGES) return;
    int c = col[e];
    int r = row[e];
    int p = row_ptr[c] + atomicAdd(&cursor[c], 1);
    epair[p] = make_int2(r, __float_as_int(dinv[r] * dinv[c]));
}

// ---------------------------------------------------------------- fused: aggregate x + layer-1 dense -> fp16 h1
// neighbor gather from the fp16 half4 array (L2-resident); self term fp32.
__global__ __launch_bounds__(256) void k_aggx_fc1(const float4* __restrict__ xp,
                                                  const half4* __restrict__ xh,
                                                  const int* __restrict__ row_ptr,
                                                  const int2* __restrict__ epair,
                                                  const float* __restrict__ dinv,
                                                  const float* __restrict__ W1,
                                                  const float* __restrict__ b1,
                                                  half_t* __restrict__ h) {
    __shared__ float sax[256][3];
    int t = threadIdx.x;
    int nb = blockIdx.x * 256;
    int i = nb + t;
    if (i < N_NODES) {
        float di = dinv[i];
        float sw = di * di;
        float4 xv = xp[i];
        float a0 = sw * xv.x, a1 = sw * xv.y, a2 = sw * xv.z;
        int s = row_ptr[i], e = row_ptr[i + 1];
        int k = s;
        for (; k + 4 <= e; k += 4) {
            int2 pr[4];
#pragma unroll
            for (int r = 0; r < 4; r++) pr[r] = epair[k + r];
            half4 bx[4];
#pragma unroll
            for (int r = 0; r < 4; r++) bx[r] = xh[pr[r].x];
#pragma unroll
            for (int r = 0; r < 4; r++) {
                float w = __int_as_float(pr[r].y);
                a0 += w * (float)bx[r].x;
                a1 += w * (float)bx[r].y;
                a2 += w * (float)bx[r].z;
            }
        }
        for (; k < e; k++) {
            int2 pr = epair[k];
            float w = __int_as_float(pr.y);
            half4 bx = xh[pr.x];
            a0 += w * (float)bx.x;
            a1 += w * (float)bx.y;
            a2 += w * (float)bx.z;
        }
        sax[t][0] = a0; sax[t][1] = a1; sax[t][2] = a2;
    }
    __syncthreads();
    int cq = t & 31, g8 = t >> 5;
    const float4* W14 = (const float4*)W1;
    float4 w0 = W14[cq], w1 = W14[32 + cq], w2 = W14[64 + cq];
    float4 bb = ((const float4*)b1)[cq];
    for (int pass = 0; pass < 32; pass++) {
        int local = pass * 8 + g8;
        int node = nb + local;
        if (node >= N_NODES) break;
        float x0 = sax[local][0], x1 = sax[local][1], x2 = sax[local][2];
        half4 o;
        o.x = (half_t)fmaxf(bb.x + x0 * w0.x + x1 * w1.x + x2 * w2.x, 0.f);
        o.y = (half_t)fmaxf(bb.y + x0 * w0.y + x1 * w1.y + x2 * w2.y, 0.f);
        o.z = (half_t)fmaxf(bb.z + x0 * w0.z + x1 * w1.z + x2 * w2.z, 0.f);
        o.w = (half_t)fmaxf(bb.w + x0 * w0.w + x1 * w1.w + x2 * w2.w, 0.f);
        ((half4*)h)[(size_t)node * 32 + cq] = o;
    }
}

// ---------------------------------------------------------------- FUSED layer: h_out = relu(Agg(h_in) @ W + b)
// TILE=16: 16 groups x 16 lanes gather ONE node each into LDS (depth-2 row
// prefetch -- the proven round-2 pipeline); 16x128x128 MFMA (wave owns a
// 16x32 quadrant, C[2]); relu-stage + coalesced write. 6250 blocks -> 3 full
// residency rounds/CU (small ramp/tail), 4.4 KB LDS, 8 blocks/CU.
__global__ __launch_bounds__(256, 8) void k_agg_mm(const half_t* __restrict__ h_in,
                                                   const int* __restrict__ row_ptr,
                                                   const int2* __restrict__ epair,
                                                   const float* __restrict__ dinv,
                                                   const half_t* __restrict__ Wt,
                                                   const float* __restrict__ b,
                                                   half_t* __restrict__ h_out) {
    __shared__ __align__(16) half_t gs[TILE][LDW];   // 4.4 KB
    int tid = threadIdx.x;
    int n0 = blockIdx.x * TILE;
    int lane16 = tid & 15;
    int gidx = tid >> 4;                  // 16 gather groups, 1 node each
    const half8* h8 = (const half8*)h_in;

    // ---- Phase A: gather (depth-2 pairwise row prefetch)
    {
        int i = n0 + gidx;               // always < N_NODES (16 | 100000)
        float di = dinv[i];
        float sw = di * di;
        half8 v = h8[(size_t)i * 16 + lane16];
        float acc[8];
#pragma unroll
        for (int c = 0; c < 8; c++) acc[c] = sw * (float)v[c];
        int s = row_ptr[i], e = row_ptr[i + 1];
        if (s < e) {
            int em1 = e - 1;
            int2 p0 = epair[s];
            int k1 = min(s + 1, em1);
            int2 p1 = epair[k1];
            float w0 = __int_as_float(p0.y);
            float w1 = (s + 1 < e) ? __int_as_float(p1.y) : 0.f;
            half8 u0 = h8[(size_t)p0.x * 16 + lane16];
            half8 u1 = h8[(size_t)p1.x * 16 + lane16];
            for (int k = s; k < e; k += 2) {
                int k2 = min(k + 2, em1);
                int k3 = min(k + 3, em1);
                int2 p2 = epair[k2];
                int2 p3 = epair[k3];
                float w2 = (k + 2 < e) ? __int_as_float(p2.y) : 0.f;
                float w3 = (k + 3 < e) ? __int_as_float(p3.y) : 0.f;
                half8 m0 = h8[(size_t)p2.x * 16 + lane16];   // next pair in flight
                half8 m1 = h8[(size_t)p3.x * 16 + lane16];
#pragma unroll
                for (int c = 0; c < 8; c++) acc[c] += w0 * (float)u0[c] + w1 * (float)u1[c];
                u0 = m0; u1 = m1; w0 = w2; w1 = w3;
            }
        }
        half8 av;
#pragma unroll
        for (int c = 0; c < 8; c++) av[c] = (half_t)acc[c];
        *(half8*)(&gs[gidx][lane16 * 8]) = av;
    }
    __syncthreads();

    // ---- Phase B: MFMA 16x128x128 from LDS; wave wv owns cols wv*32..+32
    int wv = tid >> 6;          // wave 0..3
    int ln = tid & 15;          // A-m / B-n / D-col
    int q  = (tid >> 4) & 3;    // quad
    int cbase = wv * 32;
    floatx4 C[2];
#pragma unroll
    for (int t = 0; t < 2; t++) {
        float bn = b[cbase + t * 16 + ln];
        C[t].x = bn; C[t].y = bn; C[t].z = bn; C[t].w = bn;
    }
#pragma unroll
    for (int kq = 0; kq < 4; kq++) {
        half8 a = *(const half8*)(&gs[ln][kq * 32 + q * 8]);
#pragma unroll
        for (int t = 0; t < 2; t++) {
            half8 bf = *(const half8*)(Wt + (size_t)(cbase + t * 16 + ln) * 128 + kq * 32 + q * 8);
            C[t] = __builtin_amdgcn_mfma_f32_16x16x32_f16(a, bf, C[t], 0, 0, 0);
        }
    }

    // ---- Phase C: stage relu(D) back into gs, then coalesced write
    __syncthreads();
#pragma unroll
    for (int t = 0; t < 2; t++) {
#pragma unroll
        for (int reg = 0; reg < 4; reg++) {
            float dv = (reg == 0) ? C[t].x : (reg == 1) ? C[t].y : (reg == 2) ? C[t].z : C[t].w;
            gs[q * 4 + reg][cbase + t * 16 + ln] = (half_t)fmaxf(dv, 0.f);
        }
    }
    __syncthreads();
    {
        int r0 = tid >> 4;            // 0..15
        int c0 = tid & 15;            // int4 within row (16 int4 = 128 halves)
        int4* dst = (int4*)(h_out + (size_t)(n0 + r0) * 128);
        const int4* srcp = (const int4*)(&gs[r0][0]);
        dst[c0] = srcp[c0];
    }
}

// ---------------------------------------------------------------- fused mean-pool + final FC (no atomics, vectorized)
__global__ __launch_bounds__(128) void k_pool_final(const half_t* __restrict__ h,
                                                    const int* __restrict__ batch,
                                                    const float* __restrict__ Wfc,
                                                    const float* __restrict__ bfc,
                                                    float* __restrict__ out) {
    __shared__ float sred[8][128];
    __shared__ float red[128][4];
    __shared__ int sb_s, eb_s;
    int g = blockIdx.x, t = threadIdx.x;
    if (t == 0) {
        int lo = 0, hi = N_NODES;
        while (lo < hi) { int mid = (lo + hi) >> 1; if (batch[mid] < g) lo = mid + 1; else hi = mid; }
        sb_s = lo;
        hi = N_NODES;
        while (lo < hi) { int mid = (lo + hi) >> 1; if (batch[mid] < g + 1) lo = mid + 1; else hi = mid; }
        eb_s = lo;
    }
    __syncthreads();
    int sb = sb_s, eb = eb_s;
    int lane16 = t & 15, slot = t >> 4;
    const half8* h8 = (const half8*)h;
    float acc[8];
#pragma unroll
    for (int c = 0; c < 8; c++) acc[c] = 0.f;
    for (int n = sb + slot; n < eb; n += 8) {
        half8 v = h8[(size_t)n * 16 + lane16];
#pragma unroll
        for (int c = 0; c < 8; c++) acc[c] += (float)v[c];
    }
#pragma unroll
    for (int c = 0; c < 8; c++) sred[slot][lane16 * 8 + c] = acc[c];
    __syncthreads();
    float pv = 0.f;
#pragma unroll
    for (int s2 = 0; s2 < 8; s2++) pv += sred[s2][t];
    float inv = 1.0f / fmaxf((float)(eb - sb), 1.0f);
    float v = pv * inv;
    float4 w = ((const float4*)Wfc)[t];
    red[t][0] = v * w.x; red[t][1] = v * w.y; red[t][2] = v * w.z; red[t][3] = v * w.w;
    __syncthreads();
    for (int s = 64; s > 0; s >>= 1) {
        if (t < s) {
            red[t][0] += red[t + s][0];
            red[t][1] += red[t + s][1];
            red[t][2] += red[t + s][2];
            red[t][3] += red[t + s][3];
        }
        __syncthreads();
    }
    if (t < 4) out[g * 4 + t] = red[0][t] + bfc[t];
}

// ================================================================ launch
extern "C" void kernel_launch(void* const* d_in, const int* in_sizes, int n_in,
                              void* d_out, int out_size, void* d_ws, size_t ws_size,
                              hipStream_t stream) {
    const float* x     = (const float*)d_in[0];
    const int*   ei    = (const int*)d_in[1];
    const int*   row   = ei;             // source
    const int*   col   = ei + N_EDGES;   // target (aggregation side)
    const int*   batch = (const int*)d_in[2];
    const float* W1 = (const float*)d_in[3];
    const float* b1 = (const float*)d_in[4];
    const float* W2 = (const float*)d_in[5];
    const float* b2 = (const float*)d_in[6];
    const float* W3 = (const float*)d_in[7];
    const float* b3 = (const float*)d_in[8];
    const float* W4 = (const float*)d_in[9];
    const float* b4 = (const float*)d_in[10];
    const float* Wfc = (const float*)d_in[11];
    const float* bfc = (const float*)d_in[12];
    float* out = (float*)d_out;

    char* ws = (char*)d_ws;
    size_t off = 0;
    auto take = [&](size_t bytes) -> char* {
        char* p = ws + off;
        off = (off + bytes + 255) & ~(size_t)255;
        return p;
    };
    // deg, cursor contiguous -> one memset
    int*    deg     = (int*)take(N_NODES * 4);
    int*    cursor  = (int*)take(N_NODES * 4);
    size_t  zspan   = (size_t)((char*)cursor + N_NODES * 4 - (char*)deg);
    int*    row_ptr = (int*)take((N_NODES + 1) * 4);
    int*    bsum    = (int*)take(512 * 4);
    float*  dinv    = (float*)take(N_NODES * 4);
    float4* xp      = (float4*)take((size_t)N_NODES * 16);
    half4*  xh      = (half4*)take((size_t)N_NODES * 8);
    int2*   epair   = (int2*)take((size_t)N_EDGES * 8);
    half_t* wt16    = (half_t*)take((size_t)3 * 128 * 128 * 2);
    half_t* bufA    = (half_t*)take((size_t)N_NODES * 128 * 2);
    half_t* bufB    = (half_t*)take((size_t)N_NODES * 128 * 2);

    hipMemsetAsync(deg, 0, zspan, stream);

    k_prep<<<(N_EDGES + 255) / 256, 256, 0, stream>>>(col, deg, x, xp, xh, W2, W3, W4, wt16);
    k_scan1<<<NB_SCAN, 256, 0, stream>>>(deg, row_ptr, bsum, dinv);
    k_scan3<<<NB_SCAN, 256, 0, stream>>>(row_ptr, bsum);
    k_scatter<<<(N_EDGES + 255) / 256, 256, 0, stream>>>(row, col, row_ptr, cursor,
                                                         dinv, epair);
    k_aggx_fc1<<<NB_SCAN, 256, 0, stream>>>(xp, xh, row_ptr, epair, dinv, W1, b1, bufA);

    const int NBF = N_NODES / TILE;   // 6250, exact
    // layer 2: bufA -> bufB ; layer 3: bufB -> bufA ; layer 4: bufA -> bufB
    k_agg_mm<<<NBF, 256, 0, stream>>>(bufA, row_ptr, epair, dinv, wt16,         b2, bufB);
    k_agg_mm<<<NBF, 256, 0, stream>>>(bufB, row_ptr, epair, dinv, wt16 + 16384, b3, bufA);
    k_agg_mm<<<NBF, 256, 0, stream>>>(bufA, row_ptr, epair, dinv, wt16 + 32768, b4, bufB);

    // fused mean-pool + FC (no atomics)
    k_pool_final<<<N_GRAPHS, 128, 0, stream>>>(bufB, batch, Wfc, bfc, out);
}